// Round 5
// baseline (2779.026 us; speedup 1.0000x reference)
//
#include <hip/hip_runtime.h>

static constexpr int BLK = 256;

typedef double d2 __attribute__((ext_vector_type(2)));

__device__ __forceinline__ double gelu_d(double v){
  // jax.nn.gelu approximate=True: 0.5*x*(1+tanh(sqrt(2/pi)*(x+0.044715*x^3)))
  double u = 0.7978845608028654 * (v + 0.044715 * v * v * v);
  return 0.5 * v * (1.0 + tanh(u));
}

__global__ void zero_k(int* __restrict__ a, int n){
  int stride = gridDim.x * blockDim.x;
  for (int i = blockIdx.x*blockDim.x + threadIdx.x; i < n; i += stride) a[i] = 0;
}

// ---- edge dtype probe: int64 edges have zero high words (values < 2^17) ----
__global__ void detect_k(const int* __restrict__ ei, int* __restrict__ flag){
  if (threadIdx.x == 0 && blockIdx.x == 0){
    int zeros = 0;
    for (int i = 0; i < 64; ++i) if (ei[2*i + 1] == 0) ++zeros;
    *flag = (zeros >= 48) ? 1 : 0;
  }
}

__global__ void count_k(const int* __restrict__ ei, int E, const int* __restrict__ flag,
                        int* __restrict__ cnt){
  int is64 = *flag;
  int stride = gridDim.x * blockDim.x;
  for (int e = blockIdx.x*blockDim.x + threadIdx.x; e < E; e += stride){
    int d = is64 ? ei[2*(E + e)] : ei[E + e];
    atomicAdd(&cnt[d], 1);
  }
}

__global__ void dinv_k(const int* __restrict__ cnt, double* __restrict__ dinv, int n){
  int i = blockIdx.x*blockDim.x + threadIdx.x;
  if (i < n){
    double deg = (double)(cnt[i] + 1);   // +1 self loop; always > 0
    dinv[i] = 1.0 / sqrt(deg);
  }
}

// ---- 3-phase exclusive scan over cnt[n] -> rp[n+1], 256 blocks ----
__global__ __launch_bounds__(256)
void scanA_k(const int* __restrict__ cnt, int* __restrict__ partial, int n, int chunk){
  __shared__ int red[256];
  int b = blockIdx.x;
  int lo = b * chunk, hi = min(n, lo + chunk);
  int s = 0;
  for (int i = lo + threadIdx.x; i < hi; i += 256) s += cnt[i];
  red[threadIdx.x] = s; __syncthreads();
  for (int off = 128; off > 0; off >>= 1){
    if (threadIdx.x < off) red[threadIdx.x] += red[threadIdx.x + off];
    __syncthreads();
  }
  if (threadIdx.x == 0) partial[b] = red[0];
}

__global__ __launch_bounds__(256)
void scanB_k(int* __restrict__ partial, int nb){
  __shared__ int sd[256];
  int tid = threadIdx.x;
  int v = (tid < nb) ? partial[tid] : 0;
  sd[tid] = v; __syncthreads();
  for (int off = 1; off < 256; off <<= 1){
    int t = (tid >= off) ? sd[tid - off] : 0;
    __syncthreads();
    sd[tid] += t;
    __syncthreads();
  }
  if (tid < nb) partial[tid] = sd[tid] - v;   // exclusive
  if (tid == 255) partial[nb] = sd[255];      // total
}

__global__ __launch_bounds__(256)
void scanC_k(const int* __restrict__ cnt, const int* __restrict__ partial,
             int* __restrict__ rp, int n, int chunk, int nb){
  __shared__ int sd[256];
  int b = blockIdx.x;
  int lo = b * chunk, hi = min(n, lo + chunk);
  int run = partial[b];
  for (int base = lo; base < hi; base += 256){
    int i = base + threadIdx.x;
    int v = (i < hi) ? cnt[i] : 0;
    sd[threadIdx.x] = v; __syncthreads();
    for (int off = 1; off < 256; off <<= 1){
      int t = (threadIdx.x >= off) ? sd[threadIdx.x - off] : 0;
      __syncthreads();
      sd[threadIdx.x] += t;
      __syncthreads();
    }
    if (i < hi) rp[i] = run + sd[threadIdx.x] - v;
    run += sd[255];
    __syncthreads();
  }
  if (b == 0 && threadIdx.x == 0) rp[n] = partial[nb];
}

__global__ void scatter_k(const int* __restrict__ ei, int E, const int* __restrict__ flag,
                          const int* __restrict__ rp, int* __restrict__ fill,
                          const double* __restrict__ dinv,
                          int* __restrict__ col, double* __restrict__ val){
  int is64 = *flag;
  int stride = gridDim.x * blockDim.x;
  for (int e = blockIdx.x*blockDim.x + threadIdx.x; e < E; e += stride){
    int s = is64 ? ei[2*e]       : ei[e];
    int d = is64 ? ei[2*(E + e)] : ei[E + e];
    int p = rp[d] + atomicAdd(&fill[d], 1);
    col[p] = s;
    if (val) val[p] = dinv[s];
  }
}

// h0[n x 66]: cols 0..63 = x, col 64 = t, col 65 = 0 (pad so lda is even)
template<typename ST>
__global__ void concat_k(const float* __restrict__ x, const float* __restrict__ t,
                         ST* __restrict__ h0, int n){
  int total = n * 66;
  int stride = gridDim.x * blockDim.x;
  for (int idx = blockIdx.x*blockDim.x + threadIdx.x; idx < total; idx += stride){
    int row = idx / 66;
    int c = idx - row * 66;
    float v = (c < 64) ? x[row*64 + c] : (c == 64 ? t[row] : 0.0f);
    h0[idx] = (ST)v;
  }
}

// C[n x NOUT] = A[n x K (stride lda)] @ W[K x NOUT]  (fp64 accumulate)
// 128 x (16*CT) block tile, 8 x CT per thread; rows tr+16i (conflict-free As
// reads), cols {2tc, 2tc+1, +32, +33, ...}. Register-prefetch of next k-tile.
// fuse: 0 = raw -> C ; 1 = +bias, gelu -> C ; 2 = +bias -> Cf (float, final)
// NOTE: A rows may be over-read past K up to the staged 32-double tile; caller
// guarantees the buffer extends (values are finite and multiplied by W=0).
template<typename ST, int CT>
__global__ __launch_bounds__(256, 2)
void gemm_k(const ST* __restrict__ A, int K, int lda,
            const float* __restrict__ W, int NOUT,
            const float* __restrict__ bias,
            ST* __restrict__ C, float* __restrict__ Cf,
            int n, int fuse)
{
  constexpr int TW  = 16 * CT;     // tile width in columns
  constexpr int WPT = TW / 8;      // W f32 elements staged per thread
  __shared__ __align__(16) double As[128][34];
  __shared__ __align__(16) double Ws[32][TW + 2];
  int row0 = blockIdx.x * 128;
  int col0 = blockIdx.y * TW;
  int tid = threadIdx.x;
  int tr = tid >> 4, tc = tid & 15;
  int c0 = 2 * tc;
  double acc[8][CT] = {};

  int sar = tid >> 1;              // A staging row 0..127
  int sak = (tid & 1) * 16;        // A staging col start (16 doubles/thread)
  int swr = tid >> 3;              // W staging row 0..31
  int swc = (tid & 7) * WPT;       // W staging col start

  int ktiles = (K + 31) / 32;

  double ga[16];
  float  gw[WPT];
  { // preload k-tile 0 into registers
    int gr = row0 + sar;
    const ST* Ap = A + (size_t)gr * lda + sak;
    bool rok = (gr < n);
    #pragma unroll
    for (int u = 0; u < 16; ++u) ga[u] = rok ? (double)Ap[u] : 0.0;
    const float* Wp = W + (size_t)swr * NOUT + col0 + swc;
    bool wok = (swr < K);
    #pragma unroll
    for (int u = 0; u < WPT; ++u) gw[u] = wok ? Wp[u] : 0.0f;
  }

  for (int kt = 0; kt < ktiles; ++kt){
    // regs -> LDS
    #pragma unroll
    for (int g = 0; g < 8; ++g){
      d2 v; v.x = ga[2*g]; v.y = ga[2*g+1];
      *(d2*)&As[sar][sak + 2*g] = v;
    }
    #pragma unroll
    for (int g = 0; g < WPT/2; ++g){
      d2 v; v.x = (double)gw[2*g]; v.y = (double)gw[2*g+1];
      *(d2*)&Ws[swr][swc + 2*g] = v;
    }
    __syncthreads();
    // prefetch next k-tile (latency hides under the FMA phase below)
    if (kt + 1 < ktiles){
      int k0 = (kt + 1) * 32;
      int gr = row0 + sar;
      const ST* Ap = A + (size_t)gr * lda + k0 + sak;
      bool rok = (gr < n);
      #pragma unroll
      for (int u = 0; u < 16; ++u) ga[u] = rok ? (double)Ap[u] : 0.0;
      int kg = k0 + swr;
      const float* Wp = W + (size_t)kg * NOUT + col0 + swc;
      bool wok = (kg < K);
      #pragma unroll
      for (int u = 0; u < WPT; ++u) gw[u] = wok ? Wp[u] : 0.0f;
    }
    // compute 32 k
    #pragma unroll
    for (int kk = 0; kk < 32; kk += 2){
      d2 w0[CT/2], w1[CT/2];
      #pragma unroll
      for (int q = 0; q < CT/2; ++q){
        w0[q] = *(const d2*)&Ws[kk    ][c0 + 32*q];
        w1[q] = *(const d2*)&Ws[kk + 1][c0 + 32*q];
      }
      #pragma unroll
      for (int i = 0; i < 8; ++i){
        d2 av = *(const d2*)&As[tr + 16*i][kk];
        #pragma unroll
        for (int q = 0; q < CT/2; ++q){
          acc[i][2*q  ] = fma(av.x, w0[q].x, acc[i][2*q  ]);
          acc[i][2*q+1] = fma(av.x, w0[q].y, acc[i][2*q+1]);
          acc[i][2*q  ] = fma(av.y, w1[q].x, acc[i][2*q  ]);
          acc[i][2*q+1] = fma(av.y, w1[q].y, acc[i][2*q+1]);
        }
      }
    }
    __syncthreads();
  }
  #pragma unroll
  for (int i = 0; i < 8; ++i){
    int r = row0 + tr + 16*i;
    if (r >= n) continue;
    #pragma unroll
    for (int j = 0; j < CT; ++j){
      int c = col0 + c0 + 32*(j >> 1) + (j & 1);
      double v = acc[i][j];
      if (fuse){ v += (double)bias[c]; if (fuse == 1) v = gelu_d(v); }
      if (fuse == 2) __builtin_nontemporal_store((float)v, &Cf[(size_t)r * NOUT + c]);
      else           __builtin_nontemporal_store((ST)v,   &C [(size_t)r * NOUT + c]);
    }
  }
}

// One wave per dst node i:
//   O[i,:] = dinv[i]*( sum_e val[e]*T[col[e],:] + dinv[i]*T[i,:] )   val[e]=dinv[col[e]]
//   fuse==1: O = gelu(O + bias)
template<typename ST, int NC>
__global__ __launch_bounds__(256)
void agg_k(const ST* __restrict__ T, const int* __restrict__ rp,
           const int* __restrict__ col, const double* __restrict__ val,
           const double* __restrict__ dinv, const float* __restrict__ bias,
           ST* __restrict__ O, int n, int fuse)
{
  constexpr int DOUT = NC * 64;
  int w = (blockIdx.x * blockDim.x + threadIdx.x) >> 6;
  int lane = threadIdx.x & 63;
  if (w >= n) return;
  double dv = dinv[w];
  const ST* Ti = T + (size_t)w * DOUT;
  double acc[NC];
  #pragma unroll
  for (int c = 0; c < NC; ++c) acc[c] = dv * (double)Ti[lane + 64*c];
  int e  = rp[w];
  int e1 = rp[w + 1];
  if (val){
    for (; e + 4 <= e1; e += 4){
      int s0 = __builtin_nontemporal_load(&col[e]);
      int s1 = __builtin_nontemporal_load(&col[e+1]);
      int s2 = __builtin_nontemporal_load(&col[e+2]);
      int s3 = __builtin_nontemporal_load(&col[e+3]);
      double v0 = __builtin_nontemporal_load(&val[e]);
      double v1 = __builtin_nontemporal_load(&val[e+1]);
      double v2 = __builtin_nontemporal_load(&val[e+2]);
      double v3 = __builtin_nontemporal_load(&val[e+3]);
      const ST* T0 = T + (size_t)s0 * DOUT;
      const ST* T1 = T + (size_t)s1 * DOUT;
      const ST* T2 = T + (size_t)s2 * DOUT;
      const ST* T3 = T + (size_t)s3 * DOUT;
      double t0[NC], t1[NC], t2[NC], t3[NC];
      #pragma unroll
      for (int c = 0; c < NC; ++c){
        t0[c] = (double)T0[lane + 64*c];
        t1[c] = (double)T1[lane + 64*c];
        t2[c] = (double)T2[lane + 64*c];
        t3[c] = (double)T3[lane + 64*c];
      }
      #pragma unroll
      for (int c = 0; c < NC; ++c){
        acc[c] = fma(v0, t0[c], acc[c]);
        acc[c] = fma(v1, t1[c], acc[c]);
        acc[c] = fma(v2, t2[c], acc[c]);
        acc[c] = fma(v3, t3[c], acc[c]);
      }
    }
    for (; e < e1; ++e){
      int s = __builtin_nontemporal_load(&col[e]);
      double v = __builtin_nontemporal_load(&val[e]);
      const ST* Ts = T + (size_t)s * DOUT;
      #pragma unroll
      for (int c = 0; c < NC; ++c) acc[c] = fma(v, (double)Ts[lane + 64*c], acc[c]);
    }
  } else {
    for (; e < e1; ++e){
      int s = col[e];
      double v = dinv[s];
      const ST* Ts = T + (size_t)s * DOUT;
      #pragma unroll
      for (int c = 0; c < NC; ++c) acc[c] = fma(v, (double)Ts[lane + 64*c], acc[c]);
    }
  }
  ST* Oi = O + (size_t)w * DOUT;
  #pragma unroll
  for (int c = 0; c < NC; ++c){
    double v = dv * acc[c];
    if (fuse) v = gelu_d(v + (double)bias[lane + 64*c]);
    __builtin_nontemporal_store((ST)v, &Oi[lane + 64*c]);
  }
}

template<typename ST>
static void run_net(const float* x, const float* t,
                    const float* W1, const float* b1, const float* W2, const float* b2,
                    const float* W3, const float* b3, const float* W4, const float* b4,
                    const float* F1, const float* c1, const float* F2, const float* c2,
                    const float* F3, const float* c3,
                    ST* b256, ST* ba, ST* bb,
                    const int* rp, const int* col, const double* val, const double* dinv,
                    float* out, int N, hipStream_t stream)
{
  auto gemm = [&](const ST* A, int K, int lda, const float* W, int NOUT, const float* bias,
                  ST* C, float* Cf, int fuse){
    if (NOUT >= 128){
      dim3 g((N + 127) / 128, NOUT / 128);
      gemm_k<ST,8><<<g, dim3(BLK), 0, stream>>>(A, K, lda, W, NOUT, bias, C, Cf, N, fuse);
    } else {
      dim3 g((N + 127) / 128, NOUT / 64);
      gemm_k<ST,4><<<g, dim3(BLK), 0, stream>>>(A, K, lda, W, NOUT, bias, C, Cf, N, fuse);
    }
  };
  int aggGrid = (N * 64 + BLK - 1) / BLK;   // one wave per node
  auto agg64 = [&](const ST* T, const float* bias, ST* O, int fuse){
    agg_k<ST,1><<<dim3(aggGrid), dim3(BLK), 0, stream>>>(T, rp, col, val, dinv, bias, O, N, fuse);
  };
  auto agg128 = [&](const ST* T, const float* bias, ST* O, int fuse){
    agg_k<ST,2><<<dim3(aggGrid), dim3(BLK), 0, stream>>>(T, rp, col, val, dinv, bias, O, N, fuse);
  };

  concat_k<ST><<<dim3(1024), dim3(BLK), 0, stream>>>(x, t, ba, N);  // h0(66-pad) -> BA
  gemm(ba, 65, 66, W1, 64, nullptr, bb, nullptr, 0);     // T1(64)  -> BB
  agg64(bb, b1, ba, 1);                                  // h1(64)  -> BA   gelu(Â T1 + b1)
  agg64(ba, nullptr, bb, 0);                             // g2(64)  -> BB   Â h1
  gemm(bb, 64, 64, W2, 128, b2, ba, nullptr, 1);         // h2(128) -> BA   gelu(g2 W2 + b2)
  agg128(ba, nullptr, bb, 0);                            // g3(128) -> BB   Â h2
  gemm(bb, 128, 128, W3, 256, b3, b256, nullptr, 1);     // h3(256) -> B256 gelu(g3 W3 + b3)
  gemm(b256, 256, 256, W4, 128, nullptr, ba, nullptr, 0);// T4(128) -> BA   h3 W4
  agg128(ba, b4, bb, 1);                                 // h4(128) -> BB   gelu(Â T4 + b4)
  gemm(bb, 128, 128, F1, 256, c1, b256, nullptr, 1);     // f1(256) -> B256
  gemm(b256, 256, 256, F2, 128, c2, ba, nullptr, 1);     // f2(128) -> BA
  gemm(ba, 128, 128, F3, 64, c3, nullptr, out, 2);       // out(64) -> d_out (f32)
}

extern "C" void kernel_launch(void* const* d_in, const int* in_sizes, int n_in,
                              void* d_out, int out_size, void* d_ws, size_t ws_size,
                              hipStream_t stream)
{
  const float* x  = (const float*)d_in[0];
  const float* t  = (const float*)d_in[1];
  const int*   ei = (const int*)d_in[2];
  const float* W1 = (const float*)d_in[3];  const float* b1 = (const float*)d_in[4];
  const float* W2 = (const float*)d_in[5];  const float* b2 = (const float*)d_in[6];
  const float* W3 = (const float*)d_in[7];  const float* b3 = (const float*)d_in[8];
  const float* W4 = (const float*)d_in[9];  const float* b4 = (const float*)d_in[10];
  const float* F1 = (const float*)d_in[11]; const float* c1 = (const float*)d_in[12];
  const float* F2 = (const float*)d_in[13]; const float* c2 = (const float*)d_in[14];
  const float* F3 = (const float*)d_in[15]; const float* c3 = (const float*)d_in[16];
  float* out = (float*)d_out;
  int N = in_sizes[0] / 64;
  int E = in_sizes[2] / 2;

  char* p = (char*)d_ws;
  auto alloc = [&](size_t b){ char* r = p; p += (b + 255) & ~(size_t)255; return (void*)r; };
  int*    flag    = (int*)alloc(4);
  int*    cnt     = (int*)alloc((size_t)N * 4);
  int*    fill    = (int*)alloc((size_t)N * 4);
  int*    rp      = (int*)alloc((size_t)(N + 1) * 4);
  int*    partial = (int*)alloc((size_t)257 * 4);
  int*    col     = (int*)alloc((size_t)E * 4);
  double* dinv    = (double*)alloc((size_t)N * 8);
  size_t base = (size_t)(p - (char*)d_ws);

  // activation buffers (+slack for guarded k-tile over-read on the last row)
  size_t slackB = 1024;
  size_t actElems = (size_t)N * 512;
  size_t valBytes = ((size_t)E * 8 + 255) & ~(size_t)255;
  bool f64val = ws_size >= base + valBytes + actElems * sizeof(double) + 3*slackB;
  bool f64ok  = f64val || ws_size >= base + actElems * sizeof(double) + 3*slackB;
  bool f32val = ws_size >= base + valBytes + actElems * sizeof(float) + 3*slackB;
  bool f32ok  = f32val || ws_size >= base + actElems * sizeof(float) + 3*slackB;
  if (!f32ok) return;   // cannot run without faulting; fail cleanly

  double* val = nullptr;
  if ((f64ok && f64val) || (!f64ok && f32val)) val = (double*)alloc((size_t)E * 8);

  // ---- build GCN normalization + CSR (by dst) ----
  int nb = 256;
  int chunk = (N + nb - 1) / nb;
  zero_k<<<dim3(256), dim3(BLK), 0, stream>>>(cnt, N);
  zero_k<<<dim3(256), dim3(BLK), 0, stream>>>(fill, N);
  detect_k<<<1, 64, 0, stream>>>(ei, flag);
  count_k<<<dim3(4096), dim3(BLK), 0, stream>>>(ei, E, flag, cnt);
  dinv_k<<<dim3((N + BLK - 1) / BLK), dim3(BLK), 0, stream>>>(cnt, dinv, N);
  scanA_k<<<dim3(nb), dim3(256), 0, stream>>>(cnt, partial, N, chunk);
  scanB_k<<<dim3(1), dim3(256), 0, stream>>>(partial, nb);
  scanC_k<<<dim3(nb), dim3(256), 0, stream>>>(cnt, partial, rp, N, chunk, nb);
  scatter_k<<<dim3(4096), dim3(BLK), 0, stream>>>(ei, E, flag, rp, fill, dinv, col, val);

  if (f64ok){
    double* b256 = (double*)alloc((size_t)N * 256 * 8 + slackB);
    double* ba   = (double*)alloc((size_t)N * 128 * 8 + slackB);
    double* bb   = (double*)alloc((size_t)N * 128 * 8 + slackB);
    run_net<double>(x, t, W1, b1, W2, b2, W3, b3, W4, b4, F1, c1, F2, c2, F3, c3,
                    b256, ba, bb, rp, col, val, dinv, out, N, stream);
  } else {
    float* b256 = (float*)alloc((size_t)N * 256 * 4 + slackB);
    float* ba   = (float*)alloc((size_t)N * 128 * 4 + slackB);
    float* bb   = (float*)alloc((size_t)N * 128 * 4 + slackB);
    run_net<float>(x, t, W1, b1, W2, b2, W3, b3, W4, b4, F1, c1, F2, c2, F3, c3,
                   b256, ba, bb, rp, col, val, dinv, out, N, stream);
  }
}

// Round 7
// 2525.127 us; speedup vs baseline: 1.1005x; 1.1005x over previous
//
#include <hip/hip_runtime.h>

static constexpr int BLK = 256;

typedef double d2 __attribute__((ext_vector_type(2)));

__device__ __forceinline__ double gelu_d(double v){
  // jax.nn.gelu approximate=True: 0.5*x*(1+tanh(sqrt(2/pi)*(x+0.044715*x^3)))
  double u = 0.7978845608028654 * (v + 0.044715 * v * v * v);
  return 0.5 * v * (1.0 + tanh(u));
}

__global__ void zero_k(int* __restrict__ a, int n){
  int stride = gridDim.x * blockDim.x;
  for (int i = blockIdx.x*blockDim.x + threadIdx.x; i < n; i += stride) a[i] = 0;
}

// ---- edge dtype probe: int64 edges have zero high words (values < 2^17) ----
__global__ void detect_k(const int* __restrict__ ei, int* __restrict__ flag){
  if (threadIdx.x == 0 && blockIdx.x == 0){
    int zeros = 0;
    for (int i = 0; i < 64; ++i) if (ei[2*i + 1] == 0) ++zeros;
    *flag = (zeros >= 48) ? 1 : 0;
  }
}

__global__ void count_k(const int* __restrict__ ei, int E, const int* __restrict__ flag,
                        int* __restrict__ cnt){
  int is64 = *flag;
  int stride = gridDim.x * blockDim.x;
  for (int e = blockIdx.x*blockDim.x + threadIdx.x; e < E; e += stride){
    int d = is64 ? ei[2*(E + e)] : ei[E + e];
    atomicAdd(&cnt[d], 1);
  }
}

__global__ void dinv_k(const int* __restrict__ cnt, double* __restrict__ dinv, int n){
  int i = blockIdx.x*blockDim.x + threadIdx.x;
  if (i < n){
    double deg = (double)(cnt[i] + 1);   // +1 self loop; always > 0
    dinv[i] = 1.0 / sqrt(deg);
  }
}

// ---- 3-phase exclusive scan over cnt[n] -> rp[n+1], 256 blocks ----
__global__ __launch_bounds__(256)
void scanA_k(const int* __restrict__ cnt, int* __restrict__ partial, int n, int chunk){
  __shared__ int red[256];
  int b = blockIdx.x;
  int lo = b * chunk, hi = min(n, lo + chunk);
  int s = 0;
  for (int i = lo + threadIdx.x; i < hi; i += 256) s += cnt[i];
  red[threadIdx.x] = s; __syncthreads();
  for (int off = 128; off > 0; off >>= 1){
    if (threadIdx.x < off) red[threadIdx.x] += red[threadIdx.x + off];
    __syncthreads();
  }
  if (threadIdx.x == 0) partial[b] = red[0];
}

__global__ __launch_bounds__(256)
void scanB_k(int* __restrict__ partial, int nb){
  __shared__ int sd[256];
  int tid = threadIdx.x;
  int v = (tid < nb) ? partial[tid] : 0;
  sd[tid] = v; __syncthreads();
  for (int off = 1; off < 256; off <<= 1){
    int t = (tid >= off) ? sd[tid - off] : 0;
    __syncthreads();
    sd[tid] += t;
    __syncthreads();
  }
  if (tid < nb) partial[tid] = sd[tid] - v;   // exclusive
  if (tid == 255) partial[nb] = sd[255];      // total
}

__global__ __launch_bounds__(256)
void scanC_k(const int* __restrict__ cnt, const int* __restrict__ partial,
             int* __restrict__ rp, int n, int chunk, int nb){
  __shared__ int sd[256];
  int b = blockIdx.x;
  int lo = b * chunk, hi = min(n, lo + chunk);
  int run = partial[b];
  for (int base = lo; base < hi; base += 256){
    int i = base + threadIdx.x;
    int v = (i < hi) ? cnt[i] : 0;
    sd[threadIdx.x] = v; __syncthreads();
    for (int off = 1; off < 256; off <<= 1){
      int t = (threadIdx.x >= off) ? sd[threadIdx.x - off] : 0;
      __syncthreads();
      sd[threadIdx.x] += t;
      __syncthreads();
    }
    if (i < hi) rp[i] = run + sd[threadIdx.x] - v;
    run += sd[255];
    __syncthreads();
  }
  if (b == 0 && threadIdx.x == 0) rp[n] = partial[nb];
}

__global__ void scatter_k(const int* __restrict__ ei, int E, const int* __restrict__ flag,
                          const int* __restrict__ rp, int* __restrict__ fill,
                          const double* __restrict__ dinv,
                          int* __restrict__ col, double* __restrict__ val){
  int is64 = *flag;
  int stride = gridDim.x * blockDim.x;
  for (int e = blockIdx.x*blockDim.x + threadIdx.x; e < E; e += stride){
    int s = is64 ? ei[2*e]       : ei[e];
    int d = is64 ? ei[2*(E + e)] : ei[E + e];
    int p = rp[d] + atomicAdd(&fill[d], 1);
    col[p] = s;
    if (val) val[p] = dinv[s];
  }
}

// h0[n x 66]: cols 0..63 = x, col 64 = t, col 65 = 0 (pad so lda is even)
template<typename ST>
__global__ void concat_k(const float* __restrict__ x, const float* __restrict__ t,
                         ST* __restrict__ h0, int n){
  int total = n * 66;
  int stride = gridDim.x * blockDim.x;
  for (int idx = blockIdx.x*blockDim.x + threadIdx.x; idx < total; idx += stride){
    int row = idx / 66;
    int c = idx - row * 66;
    float v = (c < 64) ? x[row*64 + c] : (c == 64 ? t[row] : 0.0f);
    h0[idx] = (ST)v;
  }
}

// C[n x NOUT] = A[n x K (stride lda)] @ W[K x NOUT]  (fp64 accumulate)
// 128x64 block tile, 8x4 per thread (rows tr+16i; cols {2tc,2tc+1,2tc+32,2tc+33}).
// fuse: 0 = raw -> C ; 1 = +bias, gelu -> C ; 2 = +bias -> Cf (float, final)
// K-tail (K=65): A over-reads to the staged 32-double boundary (caller provides
// slack; values finite), Ws zero-fills k>=K so the products are exactly 0.
template<typename ST>
__global__ __launch_bounds__(256, 2)
void gemm_k(const ST* __restrict__ A, int K, int lda,
            const float* __restrict__ W, int NOUT,
            const float* __restrict__ bias,
            ST* __restrict__ C, float* __restrict__ Cf,
            int n, int fuse)
{
  __shared__ __align__(16) double As[128][34];
  __shared__ __align__(16) double Ws[32][66];
  int row0 = blockIdx.x * 128;
  int col0 = blockIdx.y * 64;
  int tid = threadIdx.x;
  int tr = tid >> 4, tc = tid & 15;
  int c0 = 2 * tc;
  double acc[8][4] = {};
  int ktiles = (K + 31) / 32;
  for (int kt = 0; kt < ktiles; ++kt){
    int k0 = kt * 32;
    { // stage A tile 128x32: thread -> row tid>>1, 16 doubles at (tid&1)*16
      int r  = tid >> 1;
      int kk = (tid & 1) * 16;
      int gr = row0 + r;
      if constexpr (sizeof(ST) == 8){
        if (gr < n){
          const double* Ap = (const double*)A + (size_t)gr * lda + k0 + kk;
          #pragma unroll
          for (int g = 0; g < 8; ++g){
            d2 v = *(const d2*)(Ap + 2*g);      // 16B-aligned: lda even, k0+kk even
            *(d2*)&As[r][kk + 2*g] = v;
          }
        } else {
          #pragma unroll
          for (int g = 0; g < 8; ++g){ d2 z = {0.0, 0.0}; *(d2*)&As[r][kk + 2*g] = z; }
        }
      } else {
        const ST* Ap = A + (size_t)gr * lda + k0 + kk;
        #pragma unroll
        for (int u = 0; u < 16; ++u){
          int kg = k0 + kk + u;
          As[r][kk + u] = (gr < n && kg < K) ? (double)Ap[u] : 0.0;
        }
      }
    }
    { // stage W tile 32x64 (f32 -> f64); zero-fill k >= K
      int r = tid >> 3;
      int c = (tid & 7) * 8;
      int kg = k0 + r;
      if (kg < K){
        const float* Wp = W + (size_t)kg * NOUT + col0 + c;
        #pragma unroll
        for (int g = 0; g < 4; ++g){
          d2 v; v.x = (double)Wp[2*g]; v.y = (double)Wp[2*g + 1];
          *(d2*)&Ws[r][c + 2*g] = v;
        }
      } else {
        #pragma unroll
        for (int g = 0; g < 4; ++g){ d2 z = {0.0, 0.0}; *(d2*)&Ws[r][c + 2*g] = z; }
      }
    }
    __syncthreads();
    #pragma unroll
    for (int kk = 0; kk < 32; kk += 2){
      d2 w0a = *(const d2*)&Ws[kk    ][c0];
      d2 w0b = *(const d2*)&Ws[kk    ][c0 + 32];
      d2 w1a = *(const d2*)&Ws[kk + 1][c0];
      d2 w1b = *(const d2*)&Ws[kk + 1][c0 + 32];
      #pragma unroll
      for (int i = 0; i < 8; ++i){
        d2 av = *(const d2*)&As[tr + 16*i][kk];
        acc[i][0] = fma(av.x, w0a.x, acc[i][0]);
        acc[i][1] = fma(av.x, w0a.y, acc[i][1]);
        acc[i][2] = fma(av.x, w0b.x, acc[i][2]);
        acc[i][3] = fma(av.x, w0b.y, acc[i][3]);
        acc[i][0] = fma(av.y, w1a.x, acc[i][0]);
        acc[i][1] = fma(av.y, w1a.y, acc[i][1]);
        acc[i][2] = fma(av.y, w1b.x, acc[i][2]);
        acc[i][3] = fma(av.y, w1b.y, acc[i][3]);
      }
    }
    __syncthreads();
  }
  #pragma unroll
  for (int i = 0; i < 8; ++i){
    int r = row0 + tr + 16*i;
    if (r >= n) continue;
    #pragma unroll
    for (int j = 0; j < 4; ++j){
      int c = col0 + ((j < 2) ? (c0 + j) : (c0 + 30 + j));   // j=2 -> +32, j=3 -> +33
      double v = acc[i][j];
      if (fuse){ v += (double)bias[c]; if (fuse == 1) v = gelu_d(v); }
      if (fuse == 2) __builtin_nontemporal_store((float)v, &Cf[(size_t)r * NOUT + c]);
      else           __builtin_nontemporal_store((ST)v,   &C [(size_t)r * NOUT + c]);
    }
  }
}

// One wave per dst node i:
//   O[i,:] = dinv[i]*( sum_e val[e]*T[col[e],:] + dinv[i]*T[i,:] )   val[e]=dinv[col[e]]
//   fuse==1: O = gelu(O + bias)
template<typename ST, int NC>
__global__ __launch_bounds__(256)
void agg_k(const ST* __restrict__ T, const int* __restrict__ rp,
           const int* __restrict__ col, const double* __restrict__ val,
           const double* __restrict__ dinv, const float* __restrict__ bias,
           ST* __restrict__ O, int n, int fuse)
{
  constexpr int DOUT = NC * 64;
  int w = (blockIdx.x * blockDim.x + threadIdx.x) >> 6;
  int lane = threadIdx.x & 63;
  if (w >= n) return;
  double dv = dinv[w];
  const ST* Ti = T + (size_t)w * DOUT;
  double acc[NC];
  #pragma unroll
  for (int c = 0; c < NC; ++c) acc[c] = dv * (double)Ti[lane + 64*c];
  int e  = rp[w];
  int e1 = rp[w + 1];
  if (val){
    for (; e + 4 <= e1; e += 4){
      int s0 = __builtin_nontemporal_load(&col[e]);
      int s1 = __builtin_nontemporal_load(&col[e+1]);
      int s2 = __builtin_nontemporal_load(&col[e+2]);
      int s3 = __builtin_nontemporal_load(&col[e+3]);
      double v0 = __builtin_nontemporal_load(&val[e]);
      double v1 = __builtin_nontemporal_load(&val[e+1]);
      double v2 = __builtin_nontemporal_load(&val[e+2]);
      double v3 = __builtin_nontemporal_load(&val[e+3]);
      const ST* T0 = T + (size_t)s0 * DOUT;
      const ST* T1 = T + (size_t)s1 * DOUT;
      const ST* T2 = T + (size_t)s2 * DOUT;
      const ST* T3 = T + (size_t)s3 * DOUT;
      double t0[NC], t1[NC], t2[NC], t3[NC];
      #pragma unroll
      for (int c = 0; c < NC; ++c){
        t0[c] = (double)T0[lane + 64*c];
        t1[c] = (double)T1[lane + 64*c];
        t2[c] = (double)T2[lane + 64*c];
        t3[c] = (double)T3[lane + 64*c];
      }
      #pragma unroll
      for (int c = 0; c < NC; ++c){
        acc[c] = fma(v0, t0[c], acc[c]);
        acc[c] = fma(v1, t1[c], acc[c]);
        acc[c] = fma(v2, t2[c], acc[c]);
        acc[c] = fma(v3, t3[c], acc[c]);
      }
    }
    for (; e < e1; ++e){
      int s = __builtin_nontemporal_load(&col[e]);
      double v = __builtin_nontemporal_load(&val[e]);
      const ST* Ts = T + (size_t)s * DOUT;
      #pragma unroll
      for (int c = 0; c < NC; ++c) acc[c] = fma(v, (double)Ts[lane + 64*c], acc[c]);
    }
  } else {
    for (; e < e1; ++e){
      int s = col[e];
      double v = dinv[s];
      const ST* Ts = T + (size_t)s * DOUT;
      #pragma unroll
      for (int c = 0; c < NC; ++c) acc[c] = fma(v, (double)Ts[lane + 64*c], acc[c]);
    }
  }
  ST* Oi = O + (size_t)w * DOUT;
  #pragma unroll
  for (int c = 0; c < NC; ++c){
    double v = dv * acc[c];
    if (fuse) v = gelu_d(v + (double)bias[lane + 64*c]);
    __builtin_nontemporal_store((ST)v, &Oi[lane + 64*c]);
  }
}

template<typename ST>
static void run_net(const float* x, const float* t,
                    const float* W1, const float* b1, const float* W2, const float* b2,
                    const float* W3, const float* b3, const float* W4, const float* b4,
                    const float* F1, const float* c1, const float* F2, const float* c2,
                    const float* F3, const float* c3,
                    ST* b256, ST* ba, ST* bb,
                    const int* rp, const int* col, const double* val, const double* dinv,
                    float* out, int N, hipStream_t stream)
{
  auto gemm = [&](const ST* A, int K, int lda, const float* W, int NOUT, const float* bias,
                  ST* C, float* Cf, int fuse){
    dim3 g((N + 127) / 128, NOUT / 64);
    gemm_k<ST><<<g, dim3(BLK), 0, stream>>>(A, K, lda, W, NOUT, bias, C, Cf, N, fuse);
  };
  int aggGrid = (N * 64 + BLK - 1) / BLK;   // one wave per node
  auto agg64 = [&](const ST* T, const float* bias, ST* O, int fuse){
    agg_k<ST,1><<<dim3(aggGrid), dim3(BLK), 0, stream>>>(T, rp, col, val, dinv, bias, O, N, fuse);
  };
  auto agg128 = [&](const ST* T, const float* bias, ST* O, int fuse){
    agg_k<ST,2><<<dim3(aggGrid), dim3(BLK), 0, stream>>>(T, rp, col, val, dinv, bias, O, N, fuse);
  };

  concat_k<ST><<<dim3(1024), dim3(BLK), 0, stream>>>(x, t, ba, N);  // h0(66-pad) -> BA
  gemm(ba, 65, 66, W1, 64, nullptr, bb, nullptr, 0);     // T1(64)  -> BB
  agg64(bb, b1, ba, 1);                                  // h1(64)  -> BA   gelu(Â T1 + b1)
  agg64(ba, nullptr, bb, 0);                             // g2(64)  -> BB   Â h1
  gemm(bb, 64, 64, W2, 128, b2, ba, nullptr, 1);         // h2(128) -> BA   gelu(g2 W2 + b2)
  agg128(ba, nullptr, bb, 0);                            // g3(128) -> BB   Â h2
  gemm(bb, 128, 128, W3, 256, b3, b256, nullptr, 1);     // h3(256) -> B256 gelu(g3 W3 + b3)
  gemm(b256, 256, 256, W4, 128, nullptr, ba, nullptr, 0);// T4(128) -> BA   h3 W4
  agg128(ba, b4, bb, 1);                                 // h4(128) -> BB   gelu(Â T4 + b4)
  gemm(bb, 128, 128, F1, 256, c1, b256, nullptr, 1);     // f1(256) -> B256
  gemm(b256, 256, 256, F2, 128, c2, ba, nullptr, 1);     // f2(128) -> BA
  gemm(ba, 128, 128, F3, 64, c3, nullptr, out, 2);       // out(64) -> d_out (f32)
}

extern "C" void kernel_launch(void* const* d_in, const int* in_sizes, int n_in,
                              void* d_out, int out_size, void* d_ws, size_t ws_size,
                              hipStream_t stream)
{
  const float* x  = (const float*)d_in[0];
  const float* t  = (const float*)d_in[1];
  const int*   ei = (const int*)d_in[2];
  const float* W1 = (const float*)d_in[3];  const float* b1 = (const float*)d_in[4];
  const float* W2 = (const float*)d_in[5];  const float* b2 = (const float*)d_in[6];
  const float* W3 = (const float*)d_in[7];  const float* b3 = (const float*)d_in[8];
  const float* W4 = (const float*)d_in[9];  const float* b4 = (const float*)d_in[10];
  const float* F1 = (const float*)d_in[11]; const float* c1 = (const float*)d_in[12];
  const float* F2 = (const float*)d_in[13]; const float* c2 = (const float*)d_in[14];
  const float* F3 = (const float*)d_in[15]; const float* c3 = (const float*)d_in[16];
  float* out = (float*)d_out;
  int N = in_sizes[0] / 64;
  int E = in_sizes[2] / 2;

  char* p = (char*)d_ws;
  auto alloc = [&](size_t b){ char* r = p; p += (b + 255) & ~(size_t)255; return (void*)r; };
  int*    flag    = (int*)alloc(4);
  int*    cnt     = (int*)alloc((size_t)N * 4);
  int*    fill    = (int*)alloc((size_t)N * 4);
  int*    rp      = (int*)alloc((size_t)(N + 1) * 4);
  int*    partial = (int*)alloc((size_t)257 * 4);
  int*    col     = (int*)alloc((size_t)E * 4);
  double* dinv    = (double*)alloc((size_t)N * 8);
  size_t base = (size_t)(p - (char*)d_ws);

  // activation buffers (+slack for guarded k-tile over-read on the last row)
  size_t slackB = 1024;
  size_t actElems = (size_t)N * 512;
  size_t valBytes = ((size_t)E * 8 + 255) & ~(size_t)255;
  bool f64val = ws_size >= base + valBytes + actElems * sizeof(double) + 3*slackB;
  bool f64ok  = f64val || ws_size >= base + actElems * sizeof(double) + 3*slackB;
  bool f32val = ws_size >= base + valBytes + actElems * sizeof(float) + 3*slackB;
  bool f32ok  = f32val || ws_size >= base + actElems * sizeof(float) + 3*slackB;
  if (!f32ok) return;   // cannot run without faulting; fail cleanly

  double* val = nullptr;
  if ((f64ok && f64val) || (!f64ok && f32val)) val = (double*)alloc((size_t)E * 8);

  // ---- build GCN normalization + CSR (by dst) ----
  int nb = 256;
  int chunk = (N + nb - 1) / nb;
  zero_k<<<dim3(256), dim3(BLK), 0, stream>>>(cnt, N);
  zero_k<<<dim3(256), dim3(BLK), 0, stream>>>(fill, N);
  detect_k<<<1, 64, 0, stream>>>(ei, flag);
  count_k<<<dim3(4096), dim3(BLK), 0, stream>>>(ei, E, flag, cnt);
  dinv_k<<<dim3((N + BLK - 1) / BLK), dim3(BLK), 0, stream>>>(cnt, dinv, N);
  scanA_k<<<dim3(nb), dim3(256), 0, stream>>>(cnt, partial, N, chunk);
  scanB_k<<<dim3(1), dim3(256), 0, stream>>>(partial, nb);
  scanC_k<<<dim3(nb), dim3(256), 0, stream>>>(cnt, partial, rp, N, chunk, nb);
  scatter_k<<<dim3(4096), dim3(BLK), 0, stream>>>(ei, E, flag, rp, fill, dinv, col, val);

  if (f64ok){
    double* b256 = (double*)alloc((size_t)N * 256 * 8 + slackB);
    double* ba   = (double*)alloc((size_t)N * 128 * 8 + slackB);
    double* bb   = (double*)alloc((size_t)N * 128 * 8 + slackB);
    run_net<double>(x, t, W1, b1, W2, b2, W3, b3, W4, b4, F1, c1, F2, c2, F3, c3,
                    b256, ba, bb, rp, col, val, dinv, out, N, stream);
  } else {
    float* b256 = (float*)alloc((size_t)N * 256 * 4 + slackB);
    float* ba   = (float*)alloc((size_t)N * 128 * 4 + slackB);
    float* bb   = (float*)alloc((size_t)N * 128 * 4 + slackB);
    run_net<float>(x, t, W1, b1, W2, b2, W3, b3, W4, b4, F1, c1, F2, c2, F3, c3,
                   b256, ba, bb, rp, col, val, dinv, out, N, stream);
  }
}